// Round 7
// baseline (159.801 us; speedup 1.0000x reference)
//
#include <hip/hip_runtime.h>

// Problem constants
#define B_SZ   8
#define T_SEQ  2048
#define C_DIM  1024
#define H_DIM  128

typedef _Float16 half8   __attribute__((ext_vector_type(8)));
typedef _Float16 half4_t __attribute__((ext_vector_type(4)));
typedef float    f32x4   __attribute__((ext_vector_type(4)));

#define MFMA(a, b, c) __builtin_amdgcn_mfma_f32_16x16x32_f16(a, b, c, 0, 0, 0)

// Swizzled physical offset (in halfs) of logical (n, k) within one K-chunk
// of the blocked weight layout WTb[kb][...], kb = k/32.  (unchanged R6,
// proven 0 bank conflicts)
__device__ __forceinline__ int wphys(int n, int k) {
    int r = n >> 1;
    int slot = ((n & 1) << 2) | (k >> 3);
    return r * 64 + ((slot ^ (r & 7)) << 3) + (k & 7);
}

__device__ __forceinline__ void gld16(const _Float16* g, _Float16* l) {
#if __has_builtin(__builtin_amdgcn_global_load_lds)
    __builtin_amdgcn_global_load_lds(
        (const __attribute__((address_space(1))) void*)g,
        (__attribute__((address_space(3))) void*)l, 16, 0, 0);
#else
    *(half8*)l = *(const half8*)g;
#endif
}

// ---------------------------------------------------------------------------
// prep: W [C][H] fp32 -> WTb blocked-swizzled fp16 (unchanged R6).
// ---------------------------------------------------------------------------
__global__ __launch_bounds__(256) void prep_kernel(
    const float* __restrict__ Wk, const float* __restrict__ Wq,
    const float* __restrict__ Wv, _Float16* __restrict__ WTb)
{
    __shared__ _Float16 tile[64][72];

    const int w = blockIdx.y;
    const float* W = (w == 0) ? Wk : (w == 1) ? Wq : Wv;

    const int bx = blockIdx.x;
    const int c0 = (bx >> 1) * 64;
    const int h0 = (bx & 1) * 64;
    const int t  = threadIdx.x;

    {
        const int hl = (t & 15) * 4;
        const int cl = t >> 4;
        #pragma unroll
        for (int p = 0; p < 4; ++p) {
            int c = cl + p * 16;
            float4 f = *(const float4*)(W + (size_t)(c0 + c) * H_DIM + h0 + hl);
            tile[hl + 0][c] = (_Float16)f.x;
            tile[hl + 1][c] = (_Float16)f.y;
            tile[hl + 2][c] = (_Float16)f.z;
            tile[hl + 3][c] = (_Float16)f.w;
        }
    }
    __syncthreads();
    #pragma unroll
    for (int it = 0; it < 2; ++it) {
        int id = it * 256 + t;
        int hh = id >> 3, cs = id & 7;
        int n  = w * 128 + h0 + hh;
        int k8 = c0 + cs * 8;
        int kb = k8 >> 5;
        half8 v = *(const half8*)(&tile[hh][cs * 8]);
        *(half8*)(WTb + (size_t)kb * 12288 + wphys(n, k8 & 31)) = v;
    }
}

// ---------------------------------------------------------------------------
// proj: out[m][n'] = sum_k x[m][k]*W'[k][n'], M=16384 N'=384 K=1024.
// R15: T3+T4 — 3-deep circular pipeline with RAW s_barrier + COUNTED
// s_waitcnt vmcnt(4) (never 0 in steady state).  R6's version pipelined at
// source level but __syncthreads drained vmcnt(0) every step -> avg bytes
// in flight ~= 1 step briefly -> Little's law caps BW at ~1 TB/s (matches
// measured 1.03 TB/s, all pipes <10% busy).  Here 2 step-groups (8 vmem
// ops/thread) stay in flight across barriers permanently.
// Per step: 4 A-ds_reads + 3 W-ds_reads -> 12 MFMA; W via global_load_lds
// from pre-swizzled WTb (0 conflicts); x load->cvt->ds_write_b64 into a
// 36-half-stride buffer (2-way banks), write placed AFTER the counted wait.
// lgkmcnt(0) before each raw barrier (LDS visibility; 8-phase discipline).
// 512 thr, 8 waves x (64 rows x 48 cols); grid 256 = 1 block/CU; LDS 86 KB.
// ---------------------------------------------------------------------------
__global__ __launch_bounds__(512) void proj_kernel(
    const float* __restrict__ x, const _Float16* __restrict__ WTb,
    _Float16* __restrict__ q, _Float16* __restrict__ k, _Float16* __restrict__ vT)
{
    __shared__ __align__(16) _Float16 wls[3][12288];   // 72 KiB
    __shared__ __align__(16) _Float16 xls[3][64][36];  // 13.5 KiB

    const int m0 = blockIdx.x * 64;
    const int t  = threadIdx.x;
    const int wave = t >> 6, lane = t & 63;
    const int quad = lane >> 4, l15 = lane & 15;

    const int xr = t >> 3, xc = (t & 7) * 4;
    const float* xsrc = x + (size_t)(m0 + xr) * C_DIM + xc;
    const _Float16* wsrc = WTb + (size_t)t * 8;

    int aoff[4], boff[3];
    #pragma unroll
    for (int i = 0; i < 4; ++i) aoff[i] = (i * 16 + l15) * 36 + quad * 8;
    #pragma unroll
    for (int j = 0; j < 3; ++j) boff[j] = wphys(wave * 48 + j * 16 + l15, quad * 8);

    f32x4 acc[4][3] = {};
    float4 xfA, xfB, xfC;

#define VMWAIT(N) asm volatile("s_waitcnt vmcnt(" #N ")" ::: "memory")
#define LGKM0     asm volatile("s_waitcnt lgkmcnt(0)" ::: "memory")
#define BAR       __builtin_amdgcn_s_barrier()

#define WISSUE(S, B) {                                                     \
        const _Float16* ws_ = wsrc + (size_t)(S) * 12288;                  \
        gld16(ws_,        &wls[B][(size_t)t * 8]);                         \
        gld16(ws_ + 4096, &wls[B][4096 + (size_t)t * 8]);                  \
        gld16(ws_ + 8192, &wls[B][8192 + (size_t)t * 8]); }

#define XWRITE(B, XF) {                                                    \
        half4_t hv_ = { (_Float16)XF.x, (_Float16)XF.y,                    \
                        (_Float16)XF.z, (_Float16)XF.w };                  \
        *(half4_t*)(&xls[B][xr][xc]) = hv_; }

#define COMPUTE(B) {                                                       \
        half8 af_[4], bf_[3];                                              \
        _Pragma("unroll") for (int i = 0; i < 4; ++i)                      \
            af_[i] = *(const half8*)(&xls[B][0][0] + aoff[i]);             \
        _Pragma("unroll") for (int j = 0; j < 3; ++j)                      \
            bf_[j] = *(const half8*)(&wls[B][boff[j]]);                    \
        _Pragma("unroll") for (int i = 0; i < 4; ++i)                      \
            _Pragma("unroll") for (int j = 0; j < 3; ++j)                  \
                acc[i][j] = MFMA(af_[i], bf_[j], acc[i][j]); }

    // prologue: issue step-groups 0,1,2 (each = 1 x-load + 3 W gld16)
    xfA = *(const float4*)(xsrc);          WISSUE(0, 0);
    xfB = *(const float4*)(xsrc + 32);     WISSUE(1, 1);
    xfC = *(const float4*)(xsrc + 64);     WISSUE(2, 2);
    VMWAIT(8);               // group 0 landed; {1,2} in flight
    XWRITE(0, xfA);
    LGKM0; BAR;

    // steady: steps 0..26.  At step s entry: {s+1, s+2} in flight (8 ops).
    // compute(s) -> vmcnt(4) [s+1 landed] -> write x(s+1) -> bar ->
    // issue group s+3 into the buffer just freed.
    #pragma unroll 1
    for (int s = 0; s < 27; s += 3) {
        COMPUTE(0); VMWAIT(4); XWRITE(1, xfB); LGKM0; BAR;
        WISSUE(s + 3, 0); xfA = *(const float4*)(xsrc + (s + 3) * 32);
        COMPUTE(1); VMWAIT(4); XWRITE(2, xfC); LGKM0; BAR;
        WISSUE(s + 4, 1); xfB = *(const float4*)(xsrc + (s + 4) * 32);
        COMPUTE(2); VMWAIT(4); XWRITE(0, xfA); LGKM0; BAR;
        WISSUE(s + 5, 2); xfC = *(const float4*)(xsrc + (s + 5) * 32);
    }
    // s=27: issue 30
    COMPUTE(0); VMWAIT(4); XWRITE(1, xfB); LGKM0; BAR;
    WISSUE(30, 0); xfA = *(const float4*)(xsrc + 30 * 32);
    // s=28: issue 31 (last)
    COMPUTE(1); VMWAIT(4); XWRITE(2, xfC); LGKM0; BAR;
    WISSUE(31, 1); xfB = *(const float4*)(xsrc + 31 * 32);
    // s=29: {30,31} in flight -> vmcnt(4) = 30 landed
    COMPUTE(2); VMWAIT(4); XWRITE(0, xfA); LGKM0; BAR;
    // s=30: {31} in flight -> drain (only time)
    COMPUTE(0); VMWAIT(0); XWRITE(1, xfB); LGKM0; BAR;
    // s=31
    COMPUTE(1);

#undef VMWAIT
#undef LGKM0
#undef BAR
#undef WISSUE
#undef XWRITE
#undef COMPUTE

    // epilogue (unchanged R6): n' < 128 -> k, < 256 -> q, else vT
    #pragma unroll
    for (int i = 0; i < 4; ++i) {
        int grow = m0 + i * 16 + quad * 4;
        #pragma unroll
        for (int j = 0; j < 3; ++j) {
            int n = wave * 48 + j * 16 + l15;
            if (n < 256) {
                _Float16* o = (n < 128) ? k : q;
                int col = n & 127;
                #pragma unroll
                for (int r = 0; r < 4; ++r)
                    o[(size_t)(grow + r) * H_DIM + col] = (_Float16)acc[i][j][r];
            } else {
                int h  = n - 256;
                int bb = grow >> 11, tp = grow & (T_SEQ - 1);
                half4_t hv = { (_Float16)acc[i][j][0], (_Float16)acc[i][j][1],
                               (_Float16)acc[i][j][2], (_Float16)acc[i][j][3] };
                *(half4_t*)(vT + ((size_t)bb * H_DIM + h) * T_SEQ + tp) = hv;
            }
        }
    }
}

// ---------------------------------------------------------------------------
// attn: EXACT R0 version (proven ~30 us) — single-variable attribution.
// ---------------------------------------------------------------------------
__global__ __launch_bounds__(256, 3) void attn_kernel(
    const _Float16* __restrict__ q, const _Float16* __restrict__ k,
    const _Float16* __restrict__ vT,
    _Float16* __restrict__ pO, float* __restrict__ ml, float* __restrict__ out)
{
    __shared__ _Float16 ks [64][136];
    __shared__ _Float16 vts[128][72];
    __shared__ _Float16 ps [4][16][72];

    const int n = blockIdx.x;
    const int b = n & 7;
    const int u = n >> 3;

    int qt = 31, c = 0;
    {
        int acc = 0;
        #pragma unroll 1
        while (true) {
            int nch = (qt >> 3) + 1;
            if (u < acc + nch) { c = u - acc; break; }
            acc += nch; --qt;
        }
    }
    const bool partial = (qt >= 8);

    const int kt0 = c * 8;
    const int kt1 = min(qt, c * 8 + 7);

    const int t = threadIdx.x;
    const int wave = t >> 6, lane = t & 63;
    const int quad = lane >> 4, l15 = lane & 15;
    const int qrow0 = qt * 64 + wave * 16;

    const _Float16* qb = q  + (size_t)b * T_SEQ * H_DIM;
    const _Float16* kp = k  + (size_t)b * T_SEQ * H_DIM;
    const _Float16* vp = vT + (size_t)b * H_DIM * T_SEQ;

    half8 aq[4];
    #pragma unroll
    for (int i = 0; i < 4; ++i) {
        half8 v = *(const half8*)(qb + (size_t)(qrow0 + l15) * H_DIM + i * 32 + quad * 8);
        #pragma unroll
        for (int j = 0; j < 8; ++j) v[j] = v[j] * (_Float16)0.088388347648318447f;
        aq[i] = v;
    }

    f32x4 accO[8] = {};
    float lrun[4] = {0.0f, 0.0f, 0.0f, 0.0f};

    const int krow = t >> 4, kseg = t & 15;
    const int vrow = t >> 3, vseg = t & 7;

    for (int kt = kt0; kt <= kt1; ++kt) {
        const int kv0 = kt * 64;
        __syncthreads();
        #pragma unroll
        for (int p = 0; p < 4; ++p) {
            int row = p * 16 + krow;
            *(half8*)(&ks[row][kseg * 8]) =
                *(const half8*)(kp + (size_t)(kv0 + row) * H_DIM + kseg * 8);
        }
        #pragma unroll
        for (int p = 0; p < 4; ++p) {
            int h = p * 32 + vrow;
            *(half8*)(&vts[h][vseg * 8]) =
                *(const half8*)(vp + (size_t)h * T_SEQ + kv0 + vseg * 8);
        }
        __syncthreads();

        f32x4 sacc[4] = {};
        #pragma unroll
        for (int kbi = 0; kbi < 4; ++kbi) {
            #pragma unroll
            for (int nt = 0; nt < 4; ++nt) {
                half8 bf = *(const half8*)(&ks[nt * 16 + l15][kbi * 32 + quad * 8]);
                sacc[nt] = MFMA(aq[kbi], bf, sacc[nt]);
            }
        }

        if (kv0 + 63 > qrow0) {
            #pragma unroll
            for (int nt = 0; nt < 4; ++nt) {
                int key = kv0 + nt * 16 + l15;
                #pragma unroll
                for (int r = 0; r < 4; ++r) {
                    int qr = qrow0 + quad * 4 + r;
                    if (key > qr) sacc[nt][r] = -1.0e30f;
                }
            }
        }

        #pragma unroll
        for (int nt = 0; nt < 4; ++nt)
            #pragma unroll
            for (int r = 0; r < 4; ++r) {
                float p = __expf(sacc[nt][r]);
                lrun[r] += p;
                ps[wave][quad * 4 + r][nt * 16 + l15] = (_Float16)p;
            }

        half8 pf0 = *(const half8*)(&ps[wave][l15][quad * 8]);
        half8 pf1 = *(const half8*)(&ps[wave][l15][32 + quad * 8]);
        #pragma unroll
        for (int nt = 0; nt < 8; ++nt) {
            half8 vf0 = *(const half8*)(&vts[nt * 16 + l15][quad * 8]);
            half8 vf1 = *(const half8*)(&vts[nt * 16 + l15][32 + quad * 8]);
            accO[nt] = MFMA(pf0, vf0, accO[nt]);
            accO[nt] = MFMA(pf1, vf1, accO[nt]);
        }
    }

    #pragma unroll
    for (int r = 0; r < 4; ++r) {
        lrun[r] += __shfl_xor(lrun[r], 1);
        lrun[r] += __shfl_xor(lrun[r], 2);
        lrun[r] += __shfl_xor(lrun[r], 4);
        lrun[r] += __shfl_xor(lrun[r], 8);
    }

    if (partial) {
        const int pid = b * 72 + u;
        const int urow = wave * 16 + quad * 4;
        #pragma unroll
        for (int nt = 0; nt < 8; ++nt)
            #pragma unroll
            for (int r = 0; r < 4; ++r)
                pO[(size_t)pid * 8192 + (urow + r) * 128 + nt * 16 + l15]
                    = (_Float16)accO[nt][r];
        if (l15 == 0) {
            #pragma unroll
            for (int r = 0; r < 4; ++r)
                ml[(size_t)pid * 64 + urow + r] = lrun[r];
        }
    } else {
        float invl[4];
        #pragma unroll
        for (int r = 0; r < 4; ++r) invl[r] = 1.0f / lrun[r];
        #pragma unroll
        for (int nt = 0; nt < 8; ++nt)
            #pragma unroll
            for (int r = 0; r < 4; ++r)
                out[((size_t)b * T_SEQ + qrow0 + quad * 4 + r) * H_DIM + nt * 16 + l15]
                    = accO[nt][r] * invl[r];
    }
}

// ---------------------------------------------------------------------------
// combine (unchanged R0)
// ---------------------------------------------------------------------------
__global__ __launch_bounds__(256) void attn_combine(
    const _Float16* __restrict__ pO, const float* __restrict__ ml,
    float* __restrict__ out)
{
    const int n  = blockIdx.x;
    const int b  = n & 7;
    const int m  = n >> 3;
    const int rg = m & 3;
    const int qt = 8 + (m >> 2);
    const int nc = (qt >> 3) + 1;

    int u0 = 0;
    #pragma unroll 1
    for (int q2 = 31; q2 > qt; --q2) u0 += (q2 >> 3) + 1;
    const size_t pid0 = (size_t)b * 72 + u0;

    const int t   = threadIdx.x;
    const int row = rg * 16 + (t >> 4);
    const int h   = (t & 15) * 8;

    float lsum = 0.0f;
    #pragma unroll 1
    for (int c = 0; c < nc; ++c)
        lsum += ml[(pid0 + c) * 64 + row];

    float acc[8] = {};
    #pragma unroll 1
    for (int c = 0; c < nc; ++c) {
        half8 po = *(const half8*)(pO + (pid0 + c) * 8192 + row * 128 + h);
        #pragma unroll
        for (int j = 0; j < 8; ++j) acc[j] += (float)po[j];
    }

    const float inv = 1.0f / lsum;
    float* op = out + ((size_t)b * T_SEQ + qt * 64 + row) * H_DIM + h;
    f32x4 o0 = { acc[0] * inv, acc[1] * inv, acc[2] * inv, acc[3] * inv };
    f32x4 o1 = { acc[4] * inv, acc[5] * inv, acc[6] * inv, acc[7] * inv };
    *(f32x4*)(op)     = o0;
    *(f32x4*)(op + 4) = o1;
}

// ---------------------------------------------------------------------------
extern "C" void kernel_launch(void* const* d_in, const int* in_sizes, int n_in,
                              void* d_out, int out_size, void* d_ws, size_t ws_size,
                              hipStream_t stream)
{
    const float* x  = (const float*)d_in[0];
    const float* Wk = (const float*)d_in[1];
    const float* Wq = (const float*)d_in[2];
    const float* Wv = (const float*)d_in[3];
    float* out = (float*)d_out;

    _Float16* ws = (_Float16*)d_ws;
    const size_t NQKV = (size_t)B_SZ * T_SEQ * H_DIM;
    _Float16* q_ws  = ws;
    _Float16* k_ws  = ws + NQKV;
    _Float16* vT_ws = ws + 2 * NQKV;
    _Float16* wt_ws = ws + 3 * NQKV;
    _Float16* pO_ws = wt_ws + 3 * (size_t)(C_DIM * H_DIM);
    float*    ml_ws = (float*)(pO_ws + (size_t)576 * 8192);

    prep_kernel <<<dim3(32, 3), 256, 0, stream>>>(Wk, Wq, Wv, wt_ws);
    proj_kernel <<<256, 512, 0, stream>>>(x, wt_ws, q_ws, k_ws, vT_ws);
    attn_kernel <<<640, 256, 0, stream>>>(q_ws, k_ws, vT_ws, pO_ws, ml_ws, out);
    attn_combine<<<768, 256, 0, stream>>>(pO_ws, ml_ws, out);
}

// Round 8
// 157.535 us; speedup vs baseline: 1.0144x; 1.0144x over previous
//
#include <hip/hip_runtime.h>

// Problem constants
#define B_SZ   8
#define T_SEQ  2048
#define C_DIM  1024
#define H_DIM  128

typedef _Float16 half8   __attribute__((ext_vector_type(8)));
typedef _Float16 half4_t __attribute__((ext_vector_type(4)));
typedef float    f32x4   __attribute__((ext_vector_type(4)));

#define MFMA(a, b, c) __builtin_amdgcn_mfma_f32_16x16x32_f16(a, b, c, 0, 0, 0)

// ---------------------------------------------------------------------------
// prep: W [C][H] fp32 -> WT [H][C] half (3 weights), coalesced both sides
// via LDS transpose tile (R5 version, proven).  grid (32,3) x 256.
// ---------------------------------------------------------------------------
__global__ __launch_bounds__(256) void prep_kernel(
    const float* __restrict__ Wk, const float* __restrict__ Wq,
    const float* __restrict__ Wv, _Float16* __restrict__ WT_all)
{
    __shared__ _Float16 tile[64][68];

    const int w = blockIdx.y;
    const float* W = (w == 0) ? Wk : (w == 1) ? Wq : Wv;
    _Float16* dst = WT_all + (size_t)w * (C_DIM * H_DIM);

    const int bx = blockIdx.x;
    const int c0 = (bx >> 1) * 64;
    const int h0 = (bx & 1) * 64;
    const int t  = threadIdx.x;

    {
        const int hl = (t & 15) * 4;
        const int cl = t >> 4;
        #pragma unroll
        for (int p = 0; p < 4; ++p) {
            int c = cl + p * 16;
            float4 f = *(const float4*)(W + (size_t)(c0 + c) * H_DIM + h0 + hl);
            tile[hl + 0][c] = (_Float16)f.x;
            tile[hl + 1][c] = (_Float16)f.y;
            tile[hl + 2][c] = (_Float16)f.z;
            tile[hl + 3][c] = (_Float16)f.w;
        }
    }
    __syncthreads();
    {
        const int hr = t >> 4;
        const int cc = (t & 15) * 4;
        #pragma unroll
        for (int p = 0; p < 4; ++p) {
            int h = hr + p * 16;
            half4_t v = { tile[h][cc], tile[h][cc + 1], tile[h][cc + 2], tile[h][cc + 3] };
            *(half4_t*)(dst + (size_t)(h0 + h) * C_DIM + c0 + cc) = v;
        }
    }
}

// ---------------------------------------------------------------------------
// proj: out[m][n] = sum_k x[m][k]*W[k][n], M=16384 K=1024 N=128, 3 weights.
// R16: MAX-OCCUPANCY probe — the one untested axis.  Evidence: all proj
// variants (12, 6, 16, 8 waves/CU; prefetch/swizzle/bytes/counted-vmcnt)
// sit at 41-47 us with EVERY pipe <15% busy -> per-wave round-trip
// serialization (L3 ~500cy + LDS + barrier per K-step) is the binder; only
// more concurrent waves can hide it.  m-tile 32, grid (512,3) = 1536 blocks,
// LDS 23 KB, __launch_bounds__(256,6) -> 6 blocks/CU = 24 waves/CU (2x R0),
// exactly co-resident.  Same staging pattern and XCD stripe affinity
// (sharers 512 apart == same mod 8) as the 41-us R0 structure.
// w==0 -> k [B*T][H], w==1 -> q, w==2 -> vT [B][H][T] (transposed).
// ---------------------------------------------------------------------------
__global__ __launch_bounds__(256, 6) void proj_kernel(
    const float* __restrict__ x, const _Float16* __restrict__ WT_all,
    _Float16* __restrict__ q, _Float16* __restrict__ k, _Float16* __restrict__ vT)
{
    __shared__ _Float16 xs [32][72];     //  4.5 KiB
    __shared__ _Float16 wsh[128][72];    // 18   KiB

    const int w  = blockIdx.y;
    const int m0 = blockIdx.x * 32;
    const _Float16* WT = WT_all + (size_t)w * (C_DIM * H_DIM);

    const int t    = threadIdx.x;
    const int wave = t >> 6, lane = t & 63;
    const int quad = lane >> 4, l15 = lane & 15;
    const int wm = (wave >> 1) * 16;     // wave's 16-row slice
    const int wn = (wave & 1) * 64;      // wave's 64-col slice

    f32x4 acc[4] = {};

    const int xrow_ = t >> 4, xcol = (t & 15) * 4;  // x: 16 rows x 16 float4
    const int wrow_ = t >> 3, wcol = (t & 7) * 8;   // W: 32 rows x 8 half8

    for (int k0 = 0; k0 < C_DIM; k0 += 64) {
        __syncthreads();
        #pragma unroll
        for (int p = 0; p < 2; ++p) {
            int row = p * 16 + xrow_;
            float4 f = *(const float4*)(x + (size_t)(m0 + row) * C_DIM + k0 + xcol);
            half4_t hv = { (_Float16)f.x, (_Float16)f.y, (_Float16)f.z, (_Float16)f.w };
            *(half4_t*)(&xs[row][xcol]) = hv;
        }
        #pragma unroll
        for (int p = 0; p < 4; ++p) {
            int row = p * 32 + wrow_;
            *(half8*)(&wsh[row][wcol]) = *(const half8*)(WT + (size_t)row * C_DIM + k0 + wcol);
        }
        __syncthreads();
        #pragma unroll
        for (int kb = 0; kb < 2; ++kb) {
            half8 af = *(const half8*)(&xs[wm + l15][kb * 32 + quad * 8]);
            half8 bf[4];
            #pragma unroll
            for (int j = 0; j < 4; ++j)
                bf[j] = *(const half8*)(&wsh[wn + j * 16 + l15][kb * 32 + quad * 8]);
            #pragma unroll
            for (int j = 0; j < 4; ++j)
                acc[j] = MFMA(af, bf[j], acc[j]);
        }
    }

    if (w != 2) {
        _Float16* outN = (w == 0) ? k : q;
        int row = m0 + wm + quad * 4;
        #pragma unroll
        for (int j = 0; j < 4; ++j) {
            int col = wn + j * 16 + l15;
            #pragma unroll
            for (int r = 0; r < 4; ++r)
                outN[(size_t)(row + r) * H_DIM + col] = (_Float16)acc[j][r];
        }
    } else {
        int grow = m0 + wm + quad * 4;
        int bb = grow >> 11, tp = grow & (T_SEQ - 1);
        #pragma unroll
        for (int j = 0; j < 4; ++j) {
            int h = wn + j * 16 + l15;
            half4_t hv = { (_Float16)acc[j][0], (_Float16)acc[j][1],
                           (_Float16)acc[j][2], (_Float16)acc[j][3] };
            *(half4_t*)(vT + ((size_t)bb * H_DIM + h) * T_SEQ + tp) = hv;
        }
    }
}

// ---------------------------------------------------------------------------
// attn: EXACT R0 version (proven ~30 us) — single-variable attribution.
// ---------------------------------------------------------------------------
__global__ __launch_bounds__(256, 3) void attn_kernel(
    const _Float16* __restrict__ q, const _Float16* __restrict__ k,
    const _Float16* __restrict__ vT,
    _Float16* __restrict__ pO, float* __restrict__ ml, float* __restrict__ out)
{
    __shared__ _Float16 ks [64][136];
    __shared__ _Float16 vts[128][72];
    __shared__ _Float16 ps [4][16][72];

    const int n = blockIdx.x;
    const int b = n & 7;
    const int u = n >> 3;

    int qt = 31, c = 0;
    {
        int acc = 0;
        #pragma unroll 1
        while (true) {
            int nch = (qt >> 3) + 1;
            if (u < acc + nch) { c = u - acc; break; }
            acc += nch; --qt;
        }
    }
    const bool partial = (qt >= 8);

    const int kt0 = c * 8;
    const int kt1 = min(qt, c * 8 + 7);

    const int t = threadIdx.x;
    const int wave = t >> 6, lane = t & 63;
    const int quad = lane >> 4, l15 = lane & 15;
    const int qrow0 = qt * 64 + wave * 16;

    const _Float16* qb = q  + (size_t)b * T_SEQ * H_DIM;
    const _Float16* kp = k  + (size_t)b * T_SEQ * H_DIM;
    const _Float16* vp = vT + (size_t)b * H_DIM * T_SEQ;

    half8 aq[4];
    #pragma unroll
    for (int i = 0; i < 4; ++i) {
        half8 v = *(const half8*)(qb + (size_t)(qrow0 + l15) * H_DIM + i * 32 + quad * 8);
        #pragma unroll
        for (int j = 0; j < 8; ++j) v[j] = v[j] * (_Float16)0.088388347648318447f;
        aq[i] = v;
    }

    f32x4 accO[8] = {};
    float lrun[4] = {0.0f, 0.0f, 0.0f, 0.0f};

    const int krow = t >> 4, kseg = t & 15;
    const int vrow = t >> 3, vseg = t & 7;

    for (int kt = kt0; kt <= kt1; ++kt) {
        const int kv0 = kt * 64;
        __syncthreads();
        #pragma unroll
        for (int p = 0; p < 4; ++p) {
            int row = p * 16 + krow;
            *(half8*)(&ks[row][kseg * 8]) =
                *(const half8*)(kp + (size_t)(kv0 + row) * H_DIM + kseg * 8);
        }
        #pragma unroll
        for (int p = 0; p < 4; ++p) {
            int h = p * 32 + vrow;
            *(half8*)(&vts[h][vseg * 8]) =
                *(const half8*)(vp + (size_t)h * T_SEQ + kv0 + vseg * 8);
        }
        __syncthreads();

        f32x4 sacc[4] = {};
        #pragma unroll
        for (int kbi = 0; kbi < 4; ++kbi) {
            #pragma unroll
            for (int nt = 0; nt < 4; ++nt) {
                half8 bf = *(const half8*)(&ks[nt * 16 + l15][kbi * 32 + quad * 8]);
                sacc[nt] = MFMA(aq[kbi], bf, sacc[nt]);
            }
        }

        if (kv0 + 63 > qrow0) {
            #pragma unroll
            for (int nt = 0; nt < 4; ++nt) {
                int key = kv0 + nt * 16 + l15;
                #pragma unroll
                for (int r = 0; r < 4; ++r) {
                    int qr = qrow0 + quad * 4 + r;
                    if (key > qr) sacc[nt][r] = -1.0e30f;
                }
            }
        }

        #pragma unroll
        for (int nt = 0; nt < 4; ++nt)
            #pragma unroll
            for (int r = 0; r < 4; ++r) {
                float p = __expf(sacc[nt][r]);
                lrun[r] += p;
                ps[wave][quad * 4 + r][nt * 16 + l15] = (_Float16)p;
            }

        half8 pf0 = *(const half8*)(&ps[wave][l15][quad * 8]);
        half8 pf1 = *(const half8*)(&ps[wave][l15][32 + quad * 8]);
        #pragma unroll
        for (int nt = 0; nt < 8; ++nt) {
            half8 vf0 = *(const half8*)(&vts[nt * 16 + l15][quad * 8]);
            half8 vf1 = *(const half8*)(&vts[nt * 16 + l15][32 + quad * 8]);
            accO[nt] = MFMA(pf0, vf0, accO[nt]);
            accO[nt] = MFMA(pf1, vf1, accO[nt]);
        }
    }

    #pragma unroll
    for (int r = 0; r < 4; ++r) {
        lrun[r] += __shfl_xor(lrun[r], 1);
        lrun[r] += __shfl_xor(lrun[r], 2);
        lrun[r] += __shfl_xor(lrun[r], 4);
        lrun[r] += __shfl_xor(lrun[r], 8);
    }

    if (partial) {
        const int pid = b * 72 + u;
        const int urow = wave * 16 + quad * 4;
        #pragma unroll
        for (int nt = 0; nt < 8; ++nt)
            #pragma unroll
            for (int r = 0; r < 4; ++r)
                pO[(size_t)pid * 8192 + (urow + r) * 128 + nt * 16 + l15]
                    = (_Float16)accO[nt][r];
        if (l15 == 0) {
            #pragma unroll
            for (int r = 0; r < 4; ++r)
                ml[(size_t)pid * 64 + urow + r] = lrun[r];
        }
    } else {
        float invl[4];
        #pragma unroll
        for (int r = 0; r < 4; ++r) invl[r] = 1.0f / lrun[r];
        #pragma unroll
        for (int nt = 0; nt < 8; ++nt)
            #pragma unroll
            for (int r = 0; r < 4; ++r)
                out[((size_t)b * T_SEQ + qrow0 + quad * 4 + r) * H_DIM + nt * 16 + l15]
                    = accO[nt][r] * invl[r];
    }
}

// ---------------------------------------------------------------------------
// combine (unchanged R0)
// ---------------------------------------------------------------------------
__global__ __launch_bounds__(256) void attn_combine(
    const _Float16* __restrict__ pO, const float* __restrict__ ml,
    float* __restrict__ out)
{
    const int n  = blockIdx.x;
    const int b  = n & 7;
    const int m  = n >> 3;
    const int rg = m & 3;
    const int qt = 8 + (m >> 2);
    const int nc = (qt >> 3) + 1;

    int u0 = 0;
    #pragma unroll 1
    for (int q2 = 31; q2 > qt; --q2) u0 += (q2 >> 3) + 1;
    const size_t pid0 = (size_t)b * 72 + u0;

    const int t   = threadIdx.x;
    const int row = rg * 16 + (t >> 4);
    const int h   = (t & 15) * 8;

    float lsum = 0.0f;
    #pragma unroll 1
    for (int c = 0; c < nc; ++c)
        lsum += ml[(pid0 + c) * 64 + row];

    float acc[8] = {};
    #pragma unroll 1
    for (int c = 0; c < nc; ++c) {
        half8 po = *(const half8*)(pO + (pid0 + c) * 8192 + row * 128 + h);
        #pragma unroll
        for (int j = 0; j < 8; ++j) acc[j] += (float)po[j];
    }

    const float inv = 1.0f / lsum;
    float* op = out + ((size_t)b * T_SEQ + qt * 64 + row) * H_DIM + h;
    f32x4 o0 = { acc[0] * inv, acc[1] * inv, acc[2] * inv, acc[3] * inv };
    f32x4 o1 = { acc[4] * inv, acc[5] * inv, acc[6] * inv, acc[7] * inv };
    *(f32x4*)(op)     = o0;
    *(f32x4*)(op + 4) = o1;
}

// ---------------------------------------------------------------------------
extern "C" void kernel_launch(void* const* d_in, const int* in_sizes, int n_in,
                              void* d_out, int out_size, void* d_ws, size_t ws_size,
                              hipStream_t stream)
{
    const float* x  = (const float*)d_in[0];
    const float* Wk = (const float*)d_in[1];
    const float* Wq = (const float*)d_in[2];
    const float* Wv = (const float*)d_in[3];
    float* out = (float*)d_out;

    _Float16* ws = (_Float16*)d_ws;
    const size_t NQKV = (size_t)B_SZ * T_SEQ * H_DIM;
    _Float16* q_ws  = ws;
    _Float16* k_ws  = ws + NQKV;
    _Float16* vT_ws = ws + 2 * NQKV;
    _Float16* wt_ws = ws + 3 * NQKV;
    _Float16* pO_ws = wt_ws + 3 * (size_t)(C_DIM * H_DIM);
    float*    ml_ws = (float*)(pO_ws + (size_t)576 * 8192);

    prep_kernel <<<dim3(32, 3), 256, 0, stream>>>(Wk, Wq, Wv, wt_ws);
    proj_kernel <<<dim3(512, 3), 256, 0, stream>>>(x, wt_ws, q_ws, k_ws, vT_ws);
    attn_kernel <<<640, 256, 0, stream>>>(q_ws, k_ws, vT_ws, pO_ws, ml_ws, out);
    attn_combine<<<768, 256, 0, stream>>>(pO_ws, ml_ws, out);
}